// Round 1
// baseline (693.919 us; speedup 1.0000x reference)
//
#include <hip/hip_runtime.h>

#define S_LEN 2048
#define D_MODEL 2048
#define HID_DIM 5632
#define KV_DIM 512
#define QKV_DIM 3072
#define NH 32
#define NKV 8
#define HD 64
#define PS_LD 132   // padded P-tile stride (ushorts): breaks 32-bank alias for u16 writes

typedef __bf16 bf16x8 __attribute__((ext_vector_type(8)));
typedef float f32x4 __attribute__((ext_vector_type(4)));
typedef ushort us4 __attribute__((ext_vector_type(4)));
typedef ushort us8 __attribute__((ext_vector_type(8)));

__device__ __forceinline__ float bf2f(ushort u) {
    union { unsigned i; float f; } x; x.i = ((unsigned)u) << 16; return x.f;
}
__device__ __forceinline__ ushort f2bf(float f) {
    union { float f; unsigned i; } x; x.f = f;
    unsigned r = x.i + 0x7FFFu + ((x.i >> 16) & 1u);
    return (ushort)(r >> 16);
}
__device__ __forceinline__ void gll16(const ushort* g, ushort* l) {
    __builtin_amdgcn_global_load_lds(
        (const __attribute__((address_space(1))) void*)g,
        (__attribute__((address_space(3))) void*)l, 16, 0, 0);
}
// XOR-swizzle: LDS[row][g*8+j] holds global[row][(g^(row&7))*8+j].
__device__ __forceinline__ int swz_rd(int g, int qlane) { return ((g ^ (qlane & 7)) * 8); }

// ---------------------------------------------------------------- generic GEMM (bf16 out)
// C[M][N] = alpha*(A @ Bt^T). BM=128, BK=64, BN in {64,128}. grid (N/BN, M/128).
template<int BN>
__global__ __launch_bounds__(256) void gemm_bt(
    const ushort* __restrict__ A, const ushort* __restrict__ Bt, ushort* __restrict__ C,
    int K, int lda, int ldb, int ldc, float alpha)
{
    constexpr int TN = BN / 32;
    __shared__ ushort As[128 * 64];
    __shared__ ushort Bs[BN * 64];

    const int tid  = threadIdx.x;
    const int wave = tid >> 6;
    const int lane = tid & 63;
    const int qlane = lane & 15;
    const int quad  = lane >> 4;
    const int wm = (wave >> 1) * 64;
    const int wn = (wave & 1) * (BN / 2);
    const long bm0 = (long)blockIdx.y * 128;
    const long bn0 = (long)blockIdx.x * BN;

    f32x4 acc[4][TN];
#pragma unroll
    for (int i = 0; i < 4; i++)
#pragma unroll
        for (int j = 0; j < TN; j++) acc[i][j] = (f32x4){0.f,0.f,0.f,0.f};

    const int rsub = tid >> 3;
    const int csw  = ((tid & 7) ^ (rsub & 7)) * 8;   // swizzled staging column

    for (int k0 = 0; k0 < K; k0 += 64) {
#pragma unroll
        for (int i = 0; i < 4; i++)
            gll16(A + (bm0 + i*32 + rsub) * (long)lda + k0 + csw, As + (i*256 + wave*64)*8);
#pragma unroll
        for (int i = 0; i < BN/32; i++)
            gll16(Bt + (bn0 + i*32 + rsub) * (long)ldb + k0 + csw, Bs + (i*256 + wave*64)*8);
        __syncthreads();
#pragma unroll
        for (int kk = 0; kk < 64; kk += 32) {
            bf16x8 af[4], bfr[TN];
#pragma unroll
            for (int t = 0; t < 4; t++)
                af[t] = *(const bf16x8*)(As + (wm + t*16 + qlane)*64 + swz_rd((kk>>3) + quad, qlane));
#pragma unroll
            for (int t = 0; t < TN; t++)
                bfr[t] = *(const bf16x8*)(Bs + (wn + t*16 + qlane)*64 + swz_rd((kk>>3) + quad, qlane));
#pragma unroll
            for (int tm = 0; tm < 4; tm++)
#pragma unroll
                for (int tn = 0; tn < TN; tn++)
                    acc[tm][tn] = __builtin_amdgcn_mfma_f32_16x16x32_bf16(
                        af[tm], bfr[tn], acc[tm][tn], 0, 0, 0);
        }
        __syncthreads();
    }

#pragma unroll
    for (int tm = 0; tm < 4; tm++) {
        const long row = bm0 + wm + tm*16 + quad*4;
#pragma unroll
        for (int tn = 0; tn < TN; tn++) {
            const long col = bn0 + wn + tn*16 + qlane;
#pragma unroll
            for (int i = 0; i < 4; i++)
                C[(row + i) * ldc + col] = f2bf(acc[tm][tn][i] * alpha);
        }
    }
}

// ---------------------------------------------------------------- GEMM + residual (fp32 out)
template<int BN>
__global__ __launch_bounds__(256) void gemm_bt_res(
    const ushort* __restrict__ A, const ushort* __restrict__ Bt,
    const float* __restrict__ Res, float* __restrict__ Out,
    int K, int lda, int ldb, int ldc)
{
    constexpr int TN = BN / 32;
    __shared__ ushort As[128 * 64];
    __shared__ ushort Bs[BN * 64];

    const int tid  = threadIdx.x;
    const int wave = tid >> 6;
    const int lane = tid & 63;
    const int qlane = lane & 15;
    const int quad  = lane >> 4;
    const int wm = (wave >> 1) * 64;
    const int wn = (wave & 1) * (BN / 2);
    const long bm0 = (long)blockIdx.y * 128;
    const long bn0 = (long)blockIdx.x * BN;

    f32x4 acc[4][TN];
#pragma unroll
    for (int i = 0; i < 4; i++)
#pragma unroll
        for (int j = 0; j < TN; j++) acc[i][j] = (f32x4){0.f,0.f,0.f,0.f};

    const int rsub = tid >> 3;
    const int csw  = ((tid & 7) ^ (rsub & 7)) * 8;

    for (int k0 = 0; k0 < K; k0 += 64) {
#pragma unroll
        for (int i = 0; i < 4; i++)
            gll16(A + (bm0 + i*32 + rsub) * (long)lda + k0 + csw, As + (i*256 + wave*64)*8);
#pragma unroll
        for (int i = 0; i < BN/32; i++)
            gll16(Bt + (bn0 + i*32 + rsub) * (long)ldb + k0 + csw, Bs + (i*256 + wave*64)*8);
        __syncthreads();
#pragma unroll
        for (int kk = 0; kk < 64; kk += 32) {
            bf16x8 af[4], bfr[TN];
#pragma unroll
            for (int t = 0; t < 4; t++)
                af[t] = *(const bf16x8*)(As + (wm + t*16 + qlane)*64 + swz_rd((kk>>3) + quad, qlane));
#pragma unroll
            for (int t = 0; t < TN; t++)
                bfr[t] = *(const bf16x8*)(Bs + (wn + t*16 + qlane)*64 + swz_rd((kk>>3) + quad, qlane));
#pragma unroll
            for (int tm = 0; tm < 4; tm++)
#pragma unroll
                for (int tn = 0; tn < TN; tn++)
                    acc[tm][tn] = __builtin_amdgcn_mfma_f32_16x16x32_bf16(
                        af[tm], bfr[tn], acc[tm][tn], 0, 0, 0);
        }
        __syncthreads();
    }

#pragma unroll
    for (int tm = 0; tm < 4; tm++) {
        const long row = bm0 + wm + tm*16 + quad*4;
#pragma unroll
        for (int tn = 0; tn < TN; tn++) {
            const long col = bn0 + wn + tn*16 + qlane;
#pragma unroll
            for (int i = 0; i < 4; i++)
                Out[(row + i) * ldc + col] = Res[(row + i) * ldc + col] + acc[tm][tn][i];
        }
    }
}

// ---------------------------------------------------------------- fused FFN up: g = silu(A@w1T^T) * (A@w3T^T)
// BN=128: 48 KB LDS, ~196 VGPR acc+frags, 2 blocks/CU. +37% FLOP/staged-byte vs BN=64.
__global__ __launch_bounds__(256) void gemm_ffn13(
    const ushort* __restrict__ A, const ushort* __restrict__ B1t,
    const ushort* __restrict__ B3t, ushort* __restrict__ G)
{
    __shared__ ushort As[128 * 64];
    __shared__ ushort B1s[128 * 64];
    __shared__ ushort B3s[128 * 64];

    const int tid  = threadIdx.x;
    const int wave = tid >> 6;
    const int lane = tid & 63;
    const int qlane = lane & 15;
    const int quad  = lane >> 4;
    const int wm = (wave >> 1) * 64;
    const int wn = (wave & 1) * 64;
    const long bm0 = (long)blockIdx.y * 128;
    const long bn0 = (long)blockIdx.x * 128;

    f32x4 a1[4][4], a3[4][4];
#pragma unroll
    for (int i = 0; i < 4; i++)
#pragma unroll
        for (int j = 0; j < 4; j++) { a1[i][j] = (f32x4){0.f,0.f,0.f,0.f}; a3[i][j] = a1[i][j]; }

    const int rsub = tid >> 3;
    const int csw  = ((tid & 7) ^ (rsub & 7)) * 8;

    for (int k0 = 0; k0 < D_MODEL; k0 += 64) {
#pragma unroll
        for (int i = 0; i < 4; i++)
            gll16(A + (bm0 + i*32 + rsub) * (long)D_MODEL + k0 + csw, As + (i*256 + wave*64)*8);
#pragma unroll
        for (int i = 0; i < 4; i++) {
            gll16(B1t + (bn0 + i*32 + rsub) * (long)D_MODEL + k0 + csw, B1s + (i*256 + wave*64)*8);
            gll16(B3t + (bn0 + i*32 + rsub) * (long)D_MODEL + k0 + csw, B3s + (i*256 + wave*64)*8);
        }
        __syncthreads();
#pragma unroll
        for (int kk = 0; kk < 64; kk += 32) {
            bf16x8 af[4], b1f[4], b3f[4];
#pragma unroll
            for (int t = 0; t < 4; t++)
                af[t] = *(const bf16x8*)(As + (wm + t*16 + qlane)*64 + swz_rd((kk>>3) + quad, qlane));
#pragma unroll
            for (int t = 0; t < 4; t++) {
                b1f[t] = *(const bf16x8*)(B1s + (wn + t*16 + qlane)*64 + swz_rd((kk>>3) + quad, qlane));
                b3f[t] = *(const bf16x8*)(B3s + (wn + t*16 + qlane)*64 + swz_rd((kk>>3) + quad, qlane));
            }
#pragma unroll
            for (int tm = 0; tm < 4; tm++)
#pragma unroll
                for (int tn = 0; tn < 4; tn++) {
                    a1[tm][tn] = __builtin_amdgcn_mfma_f32_16x16x32_bf16(af[tm], b1f[tn], a1[tm][tn], 0,0,0);
                    a3[tm][tn] = __builtin_amdgcn_mfma_f32_16x16x32_bf16(af[tm], b3f[tn], a3[tm][tn], 0,0,0);
                }
        }
        __syncthreads();
    }

#pragma unroll
    for (int tm = 0; tm < 4; tm++) {
        const long row = bm0 + wm + tm*16 + quad*4;
#pragma unroll
        for (int tn = 0; tn < 4; tn++) {
            const long col = bn0 + wn + tn*16 + qlane;
#pragma unroll
            for (int i = 0; i < 4; i++) {
                const float u = a1[tm][tn][i];
                const float g = u / (1.f + __expf(-u)) * a3[tm][tn][i];
                G[(row + i) * HID_DIM + col] = f2bf(g);
            }
        }
    }
}

// ---------------------------------------------------------------- flash attention
// grid (NH, S_LEN/128), block 256 (4 waves x 32 q-rows). K pre-scaled by 1/8 (RoPE).
__global__ __launch_bounds__(256) void flash_attn_k(
    const ushort* __restrict__ qkv, const ushort* __restrict__ vT,
    ushort* __restrict__ attn)
{
    __shared__ ushort Ks[128 * HD];      // [k][d], swizzled groups of 8
    __shared__ ushort Vs[HD * 128];      // [d][s], swizzled groups of 8
    __shared__ ushort Ps[128 * PS_LD];   // [q][k], padded stride

    const int h = blockIdx.x;
    const int kvh = h >> 2;
    const int q0 = blockIdx.y * 128;

    const int tid = threadIdx.x;
    const int wave = tid >> 6;
    const int lane = tid & 63;
    const int qlane = lane & 15;
    const int quad = lane >> 4;
    const int wm = wave * 32;

    bf16x8 qf[2][2];
#pragma unroll
    for (int mt = 0; mt < 2; mt++)
#pragma unroll
        for (int ks = 0; ks < 2; ks++)
            qf[mt][ks] = *(const bf16x8*)(qkv + (long)(q0 + wm + mt*16 + qlane) * QKV_DIM
                                          + h * HD + ks*32 + quad*8);

    f32x4 o[2][4];
#pragma unroll
    for (int i = 0; i < 2; i++)
#pragma unroll
        for (int j = 0; j < 4; j++) o[i][j] = (f32x4){0.f,0.f,0.f,0.f};
    float mrow[2][4], lrow[2][4];
#pragma unroll
    for (int i = 0; i < 2; i++)
#pragma unroll
        for (int j = 0; j < 4; j++) { mrow[i][j] = -1e30f; lrow[i][j] = 0.f; }

    const int rsub = tid >> 3;
    const int cswk = ((tid & 7) ^ (rsub & 7)) * 8;     // K staging (8 groups/row)
    const int rsv  = tid >> 4;
    const int cswv = ((tid & 15) ^ (rsv & 7)) * 8;     // V staging (16 groups/row)
    const ushort* kbase = qkv + D_MODEL + kvh * HD;
    const ushort* vbase = vT + (long)kvh * HD * S_LEN;

    for (int k0 = 0; k0 < S_LEN; k0 += 128) {
        __syncthreads();
#pragma unroll
        for (int i = 0; i < 4; i++)
            gll16(kbase + (long)(k0 + i*32 + rsub) * QKV_DIM + cswk, Ks + (i*256 + wave*64)*8);
#pragma unroll
        for (int i = 0; i < 4; i++)
            gll16(vbase + (long)(i*16 + rsv) * S_LEN + k0 + cswv, Vs + (i*256 + wave*64)*8);
        __syncthreads();

        // S = Q Kt : per wave 32x128
        f32x4 s[2][8];
#pragma unroll
        for (int mt = 0; mt < 2; mt++)
#pragma unroll
            for (int nt = 0; nt < 8; nt++) s[mt][nt] = (f32x4){0.f,0.f,0.f,0.f};
#pragma unroll
        for (int ks = 0; ks < 2; ks++) {
            bf16x8 kf[8];
#pragma unroll
            for (int nt = 0; nt < 8; nt++)
                kf[nt] = *(const bf16x8*)(Ks + (nt*16 + qlane)*64 + swz_rd(ks*4 + quad, qlane));
            __builtin_amdgcn_s_setprio(1);
#pragma unroll
            for (int mt = 0; mt < 2; mt++)
#pragma unroll
                for (int nt = 0; nt < 8; nt++)
                    s[mt][nt] = __builtin_amdgcn_mfma_f32_16x16x32_bf16(
                        qf[mt][ks], kf[nt], s[mt][nt], 0, 0, 0);
            __builtin_amdgcn_s_setprio(0);
        }

        // online softmax
#pragma unroll
        for (int mt = 0; mt < 2; mt++) {
            float mn[4], rs[4];
#pragma unroll
            for (int i = 0; i < 4; i++) {
                float v = s[mt][0][i];
#pragma unroll
                for (int nt = 1; nt < 8; nt++) v = fmaxf(v, s[mt][nt][i]);
                mn[i] = v;
            }
#pragma unroll
            for (int i = 0; i < 4; i++) {
#pragma unroll
                for (int msk = 1; msk < 16; msk <<= 1)
                    mn[i] = fmaxf(mn[i], __shfl_xor(mn[i], msk, 64));
                mn[i] = fmaxf(mn[i], mrow[mt][i]);
            }
#pragma unroll
            for (int i = 0; i < 4; i++) {
                rs[i] = 0.f;
#pragma unroll
                for (int nt = 0; nt < 8; nt++) {
                    const float pv = __expf(s[mt][nt][i] - mn[i]);
                    s[mt][nt][i] = pv;
                    rs[i] += pv;
                }
#pragma unroll
                for (int msk = 1; msk < 16; msk <<= 1)
                    rs[i] += __shfl_xor(rs[i], msk, 64);
                const float alpha = __expf(mrow[mt][i] - mn[i]);
                mrow[mt][i] = mn[i];
                lrow[mt][i] = lrow[mt][i] * alpha + rs[i];
#pragma unroll
                for (int dt = 0; dt < 4; dt++) o[mt][dt][i] *= alpha;
            }
#pragma unroll
            for (int nt = 0; nt < 8; nt++)
#pragma unroll
                for (int i = 0; i < 4; i++)
                    Ps[(wm + mt*16 + quad*4 + i)*PS_LD + nt*16 + qlane] = f2bf(s[mt][nt][i]);
        }
        __syncthreads();

        // O += P V : per wave 32x64
#pragma unroll
        for (int kt = 0; kt < 4; kt++) {
            bf16x8 pf[2], vf[4];
#pragma unroll
            for (int mt = 0; mt < 2; mt++)
                pf[mt] = *(const bf16x8*)(Ps + (wm + mt*16 + qlane)*PS_LD + kt*32 + quad*8);
#pragma unroll
            for (int dt = 0; dt < 4; dt++)
                vf[dt] = *(const bf16x8*)(Vs + (dt*16 + qlane)*128 + swz_rd(kt*4 + quad, qlane));
            __builtin_amdgcn_s_setprio(1);
#pragma unroll
            for (int mt = 0; mt < 2; mt++)
#pragma unroll
                for (int dt = 0; dt < 4; dt++)
                    o[mt][dt] = __builtin_amdgcn_mfma_f32_16x16x32_bf16(
                        pf[mt], vf[dt], o[mt][dt], 0, 0, 0);
            __builtin_amdgcn_s_setprio(0);
        }
    }

    // epilogue: O / l
#pragma unroll
    for (int mt = 0; mt < 2; mt++)
#pragma unroll
        for (int i = 0; i < 4; i++) {
            const float inv = 1.f / lrow[mt][i];
            const long row = q0 + wm + mt*16 + quad*4 + i;
#pragma unroll
            for (int dt = 0; dt < 4; dt++)
                attn[row * D_MODEL + h*HD + dt*16 + qlane] = f2bf(o[mt][dt][i] * inv);
        }
}

// ---------------------------------------------------------------- LayerNorm (fp32 in, bf16 out)
__global__ __launch_bounds__(256) void layernorm_k(
    const float* __restrict__ x, const float* __restrict__ w,
    const float* __restrict__ b, ushort* __restrict__ out)
{
    __shared__ float red[4];
    const int row = blockIdx.x;
    const float* xr = x + (long)row * D_MODEL;
    const int wv_ = threadIdx.x >> 6, ln = threadIdx.x & 63;

    float v[8];
    float s = 0.f;
#pragma unroll
    for (int i = 0; i < 8; i++) { v[i] = xr[threadIdx.x + i*256]; s += v[i]; }
#pragma unroll
    for (int o = 32; o; o >>= 1) s += __shfl_xor(s, o, 64);
    if (ln == 0) red[wv_] = s;
    __syncthreads();
    const float mean = (red[0]+red[1]+red[2]+red[3]) * (1.f / D_MODEL);
    __syncthreads();

    float var = 0.f;
#pragma unroll
    for (int i = 0; i < 8; i++) { const float d = v[i] - mean; var += d*d; }
#pragma unroll
    for (int o = 32; o; o >>= 1) var += __shfl_xor(var, o, 64);
    if (ln == 0) red[wv_] = var;
    __syncthreads();
    var = (red[0]+red[1]+red[2]+red[3]) * (1.f / D_MODEL);
    const float rstd = rsqrtf(var + 1e-5f);

#pragma unroll
    for (int i = 0; i < 8; i++) {
        const int c = threadIdx.x + i*256;
        out[(long)row * D_MODEL + c] = f2bf((v[i] - mean) * rstd * w[c] + b[c]);
    }
}

// ---------------------------------------------------------------- RoPE in-place w/ scale
// 4 rotation pairs per thread (16B load/store); exp2f instead of powf.
__global__ __launch_bounds__(256) void rope_k(ushort* __restrict__ x, int H, int ld, float scale)
{
    const int idx = blockIdx.x * 256 + threadIdx.x;
    const int g  = idx & 7;              // group of 4 pairs
    const int h_ = (idx >> 3) % H;
    const int s  = (idx >> 3) / H;
    ushort* p = x + (long)s * ld + h_ * HD + g * 8;
    us8 v = *(const us8*)p;
#pragma unroll
    for (int j = 0; j < 4; j++) {
        const int fi = g * 4 + j;
        // powf(10000, -2*fi/64) == exp2f(-fi * log2(10000)/32)
        const float freq = exp2f((float)fi * -0.41524101186f);
        float sn, cs;
        sincosf((float)s * freq, &sn, &cs);
        const float xr = bf2f(v[2*j]), xi = bf2f(v[2*j+1]);
        v[2*j]   = f2bf((xr * cs - xi * sn) * scale);
        v[2*j+1] = f2bf((xr * sn + xi * cs) * scale);
    }
    *(us8*)p = v;
}

// ---------------------------------------------------------------- transpose + cvt (weights)
// 64x64 tile, 256 threads, float4 loads, b128 (ushort8) stores. Shapes all /64.
__global__ __launch_bounds__(256) void transcvt_k(
    const float* __restrict__ in, ushort* __restrict__ out, int ldin, int ldout)
{
    __shared__ ushort tile[64][68];      // row stride 136 B: 8B-aligned, odd bank step
    const long c0 = (long)blockIdx.x * 64, r0 = (long)blockIdx.y * 64;
    const int tid = threadIdx.x;

    const int lr = tid >> 4, lc = (tid & 15) * 4;
#pragma unroll
    for (int i = 0; i < 4; i++) {
        const float4 f = *(const float4*)(in + (r0 + lr + i*16) * (long)ldin + c0 + lc);
        us4 u; u[0] = f2bf(f.x); u[1] = f2bf(f.y); u[2] = f2bf(f.z); u[3] = f2bf(f.w);
        *(us4*)&tile[lr + i*16][lc] = u;
    }
    __syncthreads();

    const int oc = tid >> 3, orc = (tid & 7) * 8;
#pragma unroll
    for (int i = 0; i < 2; i++) {
        const int c = oc + i*32;
        us8 o;
#pragma unroll
        for (int j = 0; j < 8; j++) o[j] = tile[orc + j][c];
        *(us8*)(out + (c0 + c) * (long)ldout + r0 + orc) = o;
    }
}

// ---------------------------------------------------------------- transpose bf16 (V)
__global__ void transpose_k(const ushort* __restrict__ in, ushort* __restrict__ out,
                            int R, int C, int ldin, int ldout, long inB, long outB)
{
    __shared__ ushort tile[32][33];
    const long b = blockIdx.z;
    in += b * inB; out += b * outB;
    const int c0 = blockIdx.x * 32, r0 = blockIdx.y * 32;
    for (int i = threadIdx.y; i < 32; i += 8) {
        const int r = r0 + i, c = c0 + threadIdx.x;
        if (r < R && c < C) tile[i][threadIdx.x] = in[(long)r * ldin + c];
    }
    __syncthreads();
    for (int i = threadIdx.y; i < 32; i += 8) {
        const int c = c0 + i, r = r0 + threadIdx.x;
        if (r < R && c < C) out[(long)c * ldout + r] = tile[threadIdx.x][i];
    }
}

// ---------------------------------------------------------------- launch
extern "C" void kernel_launch(void* const* d_in, const int* in_sizes, int n_in,
                              void* d_out, int out_size, void* d_ws, size_t ws_size,
                              hipStream_t stream)
{
    const float* x   = (const float*)d_in[0];
    const float* wq  = (const float*)d_in[2];
    const float* wk  = (const float*)d_in[3];
    const float* wv  = (const float*)d_in[4];
    const float* wo  = (const float*)d_in[5];
    const float* w1  = (const float*)d_in[6];
    const float* w2  = (const float*)d_in[7];
    const float* w3  = (const float*)d_in[8];
    const float* ln1w = (const float*)d_in[9];
    const float* ln1b = (const float*)d_in[10];
    const float* ln2w = (const float*)d_in[11];
    const float* ln2b = (const float*)d_in[12];
    float* out = (float*)d_out;

    char* p = (char*)d_ws;
    auto alloc = [&](size_t bytes) {
        char* r = p; p += (bytes + 255) & ~(size_t)255; return r;
    };
    ushort* h      = (ushort*)alloc((size_t)S_LEN * D_MODEL * 2);
    ushort* qkv    = (ushort*)alloc((size_t)S_LEN * QKV_DIM * 2);
    ushort* vT     = (ushort*)alloc((size_t)NKV * HD * S_LEN * 2);
    ushort* attn   = (ushort*)alloc((size_t)S_LEN * D_MODEL * 2);
    float*  x1     = (float*) alloc((size_t)S_LEN * D_MODEL * 4);
    ushort* g1     = (ushort*)alloc((size_t)S_LEN * HID_DIM * 2);
    ushort* wqkvT  = (ushort*)alloc((size_t)QKV_DIM * D_MODEL * 2);
    ushort* woT    = (ushort*)alloc((size_t)D_MODEL * D_MODEL * 2);
    ushort* w1T    = (ushort*)alloc((size_t)D_MODEL * HID_DIM * 2);
    ushort* w2T    = (ushort*)alloc((size_t)D_MODEL * HID_DIM * 2);
    ushort* w3T    = (ushort*)alloc((size_t)D_MODEL * HID_DIM * 2);

    ushort* h2 = h;   // h dead after QKV

    const dim3 blk(256);
    const dim3 tb(32, 8);

    // weight transposes + fp32->bf16 (qkv packed -> [3072][2048])
    // grid = (C/64, R/64) for in[R][C] -> out[C][R]
    transcvt_k<<<dim3(32, 32), blk, 0, stream>>>(wq, wqkvT, D_MODEL, D_MODEL);
    transcvt_k<<<dim3(8,  32), blk, 0, stream>>>(wk, wqkvT + (size_t)D_MODEL*D_MODEL, KV_DIM, D_MODEL);
    transcvt_k<<<dim3(8,  32), blk, 0, stream>>>(wv, wqkvT + (size_t)(D_MODEL+KV_DIM)*D_MODEL, KV_DIM, D_MODEL);
    transcvt_k<<<dim3(32, 32), blk, 0, stream>>>(wo, woT, D_MODEL, D_MODEL);
    transcvt_k<<<dim3(88, 32), blk, 0, stream>>>(w1, w1T, HID_DIM, D_MODEL);
    transcvt_k<<<dim3(88, 32), blk, 0, stream>>>(w3, w3T, HID_DIM, D_MODEL);
    transcvt_k<<<dim3(32, 88), blk, 0, stream>>>(w2, w2T, D_MODEL, HID_DIM);

    // LN1
    layernorm_k<<<S_LEN, blk, 0, stream>>>(x, ln1w, ln1b, h);

    // fused QKV projection (BN=128)
    gemm_bt<128><<<dim3(QKV_DIM/128, 16), blk, 0, stream>>>(
        h, wqkvT, qkv, D_MODEL, D_MODEL, D_MODEL, QKV_DIM, 1.f);

    // RoPE (scale 1/8 folded into K); 4 pairs/thread
    rope_k<<<(S_LEN*NH*8)/256, blk, 0, stream>>>(qkv, NH, QKV_DIM, 1.f);
    rope_k<<<(S_LEN*NKV*8)/256, blk, 0, stream>>>(qkv + D_MODEL, NKV, QKV_DIM, 0.125f);

    // V transpose per KV head: vT[h][d][s]
    transpose_k<<<dim3(2, 64, NKV), tb, 0, stream>>>(
        qkv + D_MODEL + KV_DIM, vT, S_LEN, HD, QKV_DIM, S_LEN, (long)HD, (long)HD * S_LEN);

    // flash attention
    flash_attn_k<<<dim3(NH, S_LEN/128), blk, 0, stream>>>(qkv, vT, attn);

    // wo projection + residual -> fp32 x1 (BN=128)
    gemm_bt_res<128><<<dim3(16, 16), blk, 0, stream>>>(
        attn, woT, x, x1, D_MODEL, D_MODEL, D_MODEL, D_MODEL);

    // LN2 + fused FFN up + down+residual
    layernorm_k<<<S_LEN, blk, 0, stream>>>(x1, ln2w, ln2b, h2);
    gemm_ffn13<<<dim3(HID_DIM/128, 16), blk, 0, stream>>>(h2, w1T, w3T, g1);
    gemm_bt_res<128><<<dim3(16, 16), blk, 0, stream>>>(
        g1, w2T, x1, out, HID_DIM, HID_DIM, HID_DIM, D_MODEL);
}

// Round 2
// 565.964 us; speedup vs baseline: 1.2261x; 1.2261x over previous
//
#include <hip/hip_runtime.h>

#define S_LEN 2048
#define D_MODEL 2048
#define HID_DIM 5632
#define KV_DIM 512
#define QKV_DIM 3072
#define NH 32
#define NKV 8
#define HD 64
#define PS_LD 132   // padded P-tile stride (ushorts): breaks 32-bank alias for u16 writes

typedef __bf16 bf16x8 __attribute__((ext_vector_type(8)));
typedef float f32x4 __attribute__((ext_vector_type(4)));
typedef ushort us4 __attribute__((ext_vector_type(4)));
typedef ushort us8 __attribute__((ext_vector_type(8)));

__device__ __forceinline__ float bf2f(ushort u) {
    union { unsigned i; float f; } x; x.i = ((unsigned)u) << 16; return x.f;
}
__device__ __forceinline__ ushort f2bf(float f) {
    union { float f; unsigned i; } x; x.f = f;
    unsigned r = x.i + 0x7FFFu + ((x.i >> 16) & 1u);
    return (ushort)(r >> 16);
}
__device__ __forceinline__ void gll16(const ushort* g, ushort* l) {
    __builtin_amdgcn_global_load_lds(
        (const __attribute__((address_space(1))) void*)g,
        (__attribute__((address_space(3))) void*)l, 16, 0, 0);
}
// XOR-swizzle: LDS[row][g*8+j] holds global[row][(g^(row&7))*8+j].
__device__ __forceinline__ int swz_rd(int g, int qlane) { return ((g ^ (qlane & 7)) * 8); }

// ---------------------------------------------------------------- generic GEMM (bf16 out)
// C[M][N] = alpha*(A @ Bt^T). BM=128, BK=64, BN=64 (VGPR 84 -> 4 blocks/CU; BN=128
// crosses the 128-VGPR occupancy quantum and regresses 1.7x -- measured R1).
template<int BN>
__global__ __launch_bounds__(256) void gemm_bt(
    const ushort* __restrict__ A, const ushort* __restrict__ Bt, ushort* __restrict__ C,
    int K, int lda, int ldb, int ldc, float alpha)
{
    constexpr int TN = BN / 32;
    __shared__ ushort As[128 * 64];
    __shared__ ushort Bs[BN * 64];

    const int tid  = threadIdx.x;
    const int wave = tid >> 6;
    const int lane = tid & 63;
    const int qlane = lane & 15;
    const int quad  = lane >> 4;
    const int wm = (wave >> 1) * 64;
    const int wn = (wave & 1) * (BN / 2);
    const long bm0 = (long)blockIdx.y * 128;
    const long bn0 = (long)blockIdx.x * BN;

    f32x4 acc[4][TN];
#pragma unroll
    for (int i = 0; i < 4; i++)
#pragma unroll
        for (int j = 0; j < TN; j++) acc[i][j] = (f32x4){0.f,0.f,0.f,0.f};

    const int rsub = tid >> 3;
    const int csw  = ((tid & 7) ^ (rsub & 7)) * 8;   // swizzled staging column

    for (int k0 = 0; k0 < K; k0 += 64) {
#pragma unroll
        for (int i = 0; i < 4; i++)
            gll16(A + (bm0 + i*32 + rsub) * (long)lda + k0 + csw, As + (i*256 + wave*64)*8);
#pragma unroll
        for (int i = 0; i < BN/32; i++)
            gll16(Bt + (bn0 + i*32 + rsub) * (long)ldb + k0 + csw, Bs + (i*256 + wave*64)*8);
        __syncthreads();
#pragma unroll
        for (int kk = 0; kk < 64; kk += 32) {
            bf16x8 af[4], bfr[TN];
#pragma unroll
            for (int t = 0; t < 4; t++)
                af[t] = *(const bf16x8*)(As + (wm + t*16 + qlane)*64 + swz_rd((kk>>3) + quad, qlane));
#pragma unroll
            for (int t = 0; t < TN; t++)
                bfr[t] = *(const bf16x8*)(Bs + (wn + t*16 + qlane)*64 + swz_rd((kk>>3) + quad, qlane));
#pragma unroll
            for (int tm = 0; tm < 4; tm++)
#pragma unroll
                for (int tn = 0; tn < TN; tn++)
                    acc[tm][tn] = __builtin_amdgcn_mfma_f32_16x16x32_bf16(
                        af[tm], bfr[tn], acc[tm][tn], 0, 0, 0);
        }
        __syncthreads();
    }

#pragma unroll
    for (int tm = 0; tm < 4; tm++) {
        const long row = bm0 + wm + tm*16 + quad*4;
#pragma unroll
        for (int tn = 0; tn < TN; tn++) {
            const long col = bn0 + wn + tn*16 + qlane;
#pragma unroll
            for (int i = 0; i < 4; i++)
                C[(row + i) * ldc + col] = f2bf(acc[tm][tn][i] * alpha);
        }
    }
}

// ---------------------------------------------------------------- GEMM + residual (fp32 out)
__global__ __launch_bounds__(256) void gemm_bt_res(
    const ushort* __restrict__ A, const ushort* __restrict__ Bt,
    const float* __restrict__ Res, float* __restrict__ Out,
    int K, int lda, int ldb, int ldc)
{
    __shared__ ushort As[128 * 64];
    __shared__ ushort Bs[64 * 64];

    const int tid  = threadIdx.x;
    const int wave = tid >> 6;
    const int lane = tid & 63;
    const int qlane = lane & 15;
    const int quad  = lane >> 4;
    const int wm = (wave >> 1) * 64;
    const int wn = (wave & 1) * 32;
    const long bm0 = (long)blockIdx.y * 128;
    const long bn0 = (long)blockIdx.x * 64;

    f32x4 acc[4][2];
#pragma unroll
    for (int i = 0; i < 4; i++)
#pragma unroll
        for (int j = 0; j < 2; j++) acc[i][j] = (f32x4){0.f,0.f,0.f,0.f};

    const int rsub = tid >> 3;
    const int csw  = ((tid & 7) ^ (rsub & 7)) * 8;

    for (int k0 = 0; k0 < K; k0 += 64) {
#pragma unroll
        for (int i = 0; i < 4; i++)
            gll16(A + (bm0 + i*32 + rsub) * (long)lda + k0 + csw, As + (i*256 + wave*64)*8);
#pragma unroll
        for (int i = 0; i < 2; i++)
            gll16(Bt + (bn0 + i*32 + rsub) * (long)ldb + k0 + csw, Bs + (i*256 + wave*64)*8);
        __syncthreads();
#pragma unroll
        for (int kk = 0; kk < 64; kk += 32) {
            bf16x8 af[4], bfr[2];
#pragma unroll
            for (int t = 0; t < 4; t++)
                af[t] = *(const bf16x8*)(As + (wm + t*16 + qlane)*64 + swz_rd((kk>>3) + quad, qlane));
#pragma unroll
            for (int t = 0; t < 2; t++)
                bfr[t] = *(const bf16x8*)(Bs + (wn + t*16 + qlane)*64 + swz_rd((kk>>3) + quad, qlane));
#pragma unroll
            for (int tm = 0; tm < 4; tm++)
#pragma unroll
                for (int tn = 0; tn < 2; tn++)
                    acc[tm][tn] = __builtin_amdgcn_mfma_f32_16x16x32_bf16(
                        af[tm], bfr[tn], acc[tm][tn], 0, 0, 0);
        }
        __syncthreads();
    }

#pragma unroll
    for (int tm = 0; tm < 4; tm++) {
        const long row = bm0 + wm + tm*16 + quad*4;
#pragma unroll
        for (int tn = 0; tn < 2; tn++) {
            const long col = bn0 + wn + tn*16 + qlane;
#pragma unroll
            for (int i = 0; i < 4; i++)
                Out[(row + i) * ldc + col] = Res[(row + i) * ldc + col] + acc[tm][tn][i];
        }
    }
}

// ---------------------------------------------------------------- fused FFN up: g = silu(A@w1T^T) * (A@w3T^T)
__global__ __launch_bounds__(256) void gemm_ffn13(
    const ushort* __restrict__ A, const ushort* __restrict__ B1t,
    const ushort* __restrict__ B3t, ushort* __restrict__ G)
{
    __shared__ ushort As[128 * 64];
    __shared__ ushort B1s[64 * 64];
    __shared__ ushort B3s[64 * 64];

    const int tid  = threadIdx.x;
    const int wave = tid >> 6;
    const int lane = tid & 63;
    const int qlane = lane & 15;
    const int quad  = lane >> 4;
    const int wm = (wave >> 1) * 64;
    const int wn = (wave & 1) * 32;
    const long bm0 = (long)blockIdx.y * 128;
    const long bn0 = (long)blockIdx.x * 64;

    f32x4 a1[4][2], a3[4][2];
#pragma unroll
    for (int i = 0; i < 4; i++)
#pragma unroll
        for (int j = 0; j < 2; j++) { a1[i][j] = (f32x4){0.f,0.f,0.f,0.f}; a3[i][j] = a1[i][j]; }

    const int rsub = tid >> 3;
    const int csw  = ((tid & 7) ^ (rsub & 7)) * 8;

    for (int k0 = 0; k0 < D_MODEL; k0 += 64) {
#pragma unroll
        for (int i = 0; i < 4; i++)
            gll16(A + (bm0 + i*32 + rsub) * (long)D_MODEL + k0 + csw, As + (i*256 + wave*64)*8);
#pragma unroll
        for (int i = 0; i < 2; i++) {
            gll16(B1t + (bn0 + i*32 + rsub) * (long)D_MODEL + k0 + csw, B1s + (i*256 + wave*64)*8);
            gll16(B3t + (bn0 + i*32 + rsub) * (long)D_MODEL + k0 + csw, B3s + (i*256 + wave*64)*8);
        }
        __syncthreads();
#pragma unroll
        for (int kk = 0; kk < 64; kk += 32) {
            bf16x8 af[4], b1f[2], b3f[2];
#pragma unroll
            for (int t = 0; t < 4; t++)
                af[t] = *(const bf16x8*)(As + (wm + t*16 + qlane)*64 + swz_rd((kk>>3) + quad, qlane));
#pragma unroll
            for (int t = 0; t < 2; t++) {
                b1f[t] = *(const bf16x8*)(B1s + (wn + t*16 + qlane)*64 + swz_rd((kk>>3) + quad, qlane));
                b3f[t] = *(const bf16x8*)(B3s + (wn + t*16 + qlane)*64 + swz_rd((kk>>3) + quad, qlane));
            }
#pragma unroll
            for (int tm = 0; tm < 4; tm++)
#pragma unroll
                for (int tn = 0; tn < 2; tn++) {
                    a1[tm][tn] = __builtin_amdgcn_mfma_f32_16x16x32_bf16(af[tm], b1f[tn], a1[tm][tn], 0,0,0);
                    a3[tm][tn] = __builtin_amdgcn_mfma_f32_16x16x32_bf16(af[tm], b3f[tn], a3[tm][tn], 0,0,0);
                }
        }
        __syncthreads();
    }

#pragma unroll
    for (int tm = 0; tm < 4; tm++) {
        const long row = bm0 + wm + tm*16 + quad*4;
#pragma unroll
        for (int tn = 0; tn < 2; tn++) {
            const long col = bn0 + wn + tn*16 + qlane;
#pragma unroll
            for (int i = 0; i < 4; i++) {
                const float u = a1[tm][tn][i];
                const float g = u / (1.f + __expf(-u)) * a3[tm][tn][i];
                G[(row + i) * HID_DIM + col] = f2bf(g);
            }
        }
    }
}

// ---------------------------------------------------------------- flash attention
// grid (NH, S_LEN/128), block 256 (4 waves x 32 q-rows). K pre-scaled by 1/8 (RoPE).
__global__ __launch_bounds__(256) void flash_attn_k(
    const ushort* __restrict__ qkv, const ushort* __restrict__ vT,
    ushort* __restrict__ attn)
{
    __shared__ ushort Ks[128 * HD];      // [k][d], swizzled groups of 8
    __shared__ ushort Vs[HD * 128];      // [d][s], swizzled groups of 8
    __shared__ ushort Ps[128 * PS_LD];   // [q][k], padded stride

    const int h = blockIdx.x;
    const int kvh = h >> 2;
    const int q0 = blockIdx.y * 128;

    const int tid = threadIdx.x;
    const int wave = tid >> 6;
    const int lane = tid & 63;
    const int qlane = lane & 15;
    const int quad = lane >> 4;
    const int wm = wave * 32;

    bf16x8 qf[2][2];
#pragma unroll
    for (int mt = 0; mt < 2; mt++)
#pragma unroll
        for (int ks = 0; ks < 2; ks++)
            qf[mt][ks] = *(const bf16x8*)(qkv + (long)(q0 + wm + mt*16 + qlane) * QKV_DIM
                                          + h * HD + ks*32 + quad*8);

    f32x4 o[2][4];
#pragma unroll
    for (int i = 0; i < 2; i++)
#pragma unroll
        for (int j = 0; j < 4; j++) o[i][j] = (f32x4){0.f,0.f,0.f,0.f};
    float mrow[2][4], lrow[2][4];
#pragma unroll
    for (int i = 0; i < 2; i++)
#pragma unroll
        for (int j = 0; j < 4; j++) { mrow[i][j] = -1e30f; lrow[i][j] = 0.f; }

    const int rsub = tid >> 3;
    const int cswk = ((tid & 7) ^ (rsub & 7)) * 8;     // K staging (8 groups/row)
    const int rsv  = tid >> 4;
    const int cswv = ((tid & 15) ^ (rsv & 7)) * 8;     // V staging (16 groups/row)
    const ushort* kbase = qkv + D_MODEL + kvh * HD;
    const ushort* vbase = vT + (long)kvh * HD * S_LEN;

    for (int k0 = 0; k0 < S_LEN; k0 += 128) {
        __syncthreads();
#pragma unroll
        for (int i = 0; i < 4; i++)
            gll16(kbase + (long)(k0 + i*32 + rsub) * QKV_DIM + cswk, Ks + (i*256 + wave*64)*8);
#pragma unroll
        for (int i = 0; i < 4; i++)
            gll16(vbase + (long)(i*16 + rsv) * S_LEN + k0 + cswv, Vs + (i*256 + wave*64)*8);
        __syncthreads();

        // S = Q Kt : per wave 32x128
        f32x4 s[2][8];
#pragma unroll
        for (int mt = 0; mt < 2; mt++)
#pragma unroll
            for (int nt = 0; nt < 8; nt++) s[mt][nt] = (f32x4){0.f,0.f,0.f,0.f};
#pragma unroll
        for (int ks = 0; ks < 2; ks++) {
            bf16x8 kf[8];
#pragma unroll
            for (int nt = 0; nt < 8; nt++)
                kf[nt] = *(const bf16x8*)(Ks + (nt*16 + qlane)*64 + swz_rd(ks*4 + quad, qlane));
            __builtin_amdgcn_s_setprio(1);
#pragma unroll
            for (int mt = 0; mt < 2; mt++)
#pragma unroll
                for (int nt = 0; nt < 8; nt++)
                    s[mt][nt] = __builtin_amdgcn_mfma_f32_16x16x32_bf16(
                        qf[mt][ks], kf[nt], s[mt][nt], 0, 0, 0);
            __builtin_amdgcn_s_setprio(0);
        }

        // online softmax
#pragma unroll
        for (int mt = 0; mt < 2; mt++) {
            float mn[4], rs[4];
#pragma unroll
            for (int i = 0; i < 4; i++) {
                float v = s[mt][0][i];
#pragma unroll
                for (int nt = 1; nt < 8; nt++) v = fmaxf(v, s[mt][nt][i]);
                mn[i] = v;
            }
#pragma unroll
            for (int i = 0; i < 4; i++) {
#pragma unroll
                for (int msk = 1; msk < 16; msk <<= 1)
                    mn[i] = fmaxf(mn[i], __shfl_xor(mn[i], msk, 64));
                mn[i] = fmaxf(mn[i], mrow[mt][i]);
            }
#pragma unroll
            for (int i = 0; i < 4; i++) {
                rs[i] = 0.f;
#pragma unroll
                for (int nt = 0; nt < 8; nt++) {
                    const float pv = __expf(s[mt][nt][i] - mn[i]);
                    s[mt][nt][i] = pv;
                    rs[i] += pv;
                }
#pragma unroll
                for (int msk = 1; msk < 16; msk <<= 1)
                    rs[i] += __shfl_xor(rs[i], msk, 64);
                const float alpha = __expf(mrow[mt][i] - mn[i]);
                mrow[mt][i] = mn[i];
                lrow[mt][i] = lrow[mt][i] * alpha + rs[i];
#pragma unroll
                for (int dt = 0; dt < 4; dt++) o[mt][dt][i] *= alpha;
            }
#pragma unroll
            for (int nt = 0; nt < 8; nt++)
#pragma unroll
                for (int i = 0; i < 4; i++)
                    Ps[(wm + mt*16 + quad*4 + i)*PS_LD + nt*16 + qlane] = f2bf(s[mt][nt][i]);
        }
        __syncthreads();

        // O += P V : per wave 32x64
#pragma unroll
        for (int kt = 0; kt < 4; kt++) {
            bf16x8 pf[2], vf[4];
#pragma unroll
            for (int mt = 0; mt < 2; mt++)
                pf[mt] = *(const bf16x8*)(Ps + (wm + mt*16 + qlane)*PS_LD + kt*32 + quad*8);
#pragma unroll
            for (int dt = 0; dt < 4; dt++)
                vf[dt] = *(const bf16x8*)(Vs + (dt*16 + qlane)*128 + swz_rd(kt*4 + quad, qlane));
            __builtin_amdgcn_s_setprio(1);
#pragma unroll
            for (int mt = 0; mt < 2; mt++)
#pragma unroll
                for (int dt = 0; dt < 4; dt++)
                    o[mt][dt] = __builtin_amdgcn_mfma_f32_16x16x32_bf16(
                        pf[mt], vf[dt], o[mt][dt], 0, 0, 0);
            __builtin_amdgcn_s_setprio(0);
        }
    }

    // epilogue: O / l
#pragma unroll
    for (int mt = 0; mt < 2; mt++)
#pragma unroll
        for (int i = 0; i < 4; i++) {
            const float inv = 1.f / lrow[mt][i];
            const long row = q0 + wm + mt*16 + quad*4 + i;
#pragma unroll
            for (int dt = 0; dt < 4; dt++)
                attn[row * D_MODEL + h*HD + dt*16 + qlane] = f2bf(o[mt][dt][i] * inv);
        }
}

// ---------------------------------------------------------------- LayerNorm (fp32 in, bf16 out)
// float4 loads (8 contiguous elems/thread), ushort8 store.
__global__ __launch_bounds__(256) void layernorm_k(
    const float* __restrict__ x, const float* __restrict__ w,
    const float* __restrict__ b, ushort* __restrict__ out)
{
    __shared__ float red[4];
    const int row = blockIdx.x;
    const int tid = threadIdx.x;
    const float* xr = x + (long)row * D_MODEL + tid * 8;
    const int wv_ = tid >> 6, ln = tid & 63;

    float4 v0 = *(const float4*)xr;
    float4 v1 = *(const float4*)(xr + 4);
    float s = v0.x + v0.y + v0.z + v0.w + v1.x + v1.y + v1.z + v1.w;
#pragma unroll
    for (int o = 32; o; o >>= 1) s += __shfl_xor(s, o, 64);
    if (ln == 0) red[wv_] = s;
    __syncthreads();
    const float mean = (red[0]+red[1]+red[2]+red[3]) * (1.f / D_MODEL);
    __syncthreads();

    float e[8] = {v0.x, v0.y, v0.z, v0.w, v1.x, v1.y, v1.z, v1.w};
    float var = 0.f;
#pragma unroll
    for (int i = 0; i < 8; i++) { const float d = e[i] - mean; var += d*d; }
#pragma unroll
    for (int o = 32; o; o >>= 1) var += __shfl_xor(var, o, 64);
    if (ln == 0) red[wv_] = var;
    __syncthreads();
    var = (red[0]+red[1]+red[2]+red[3]) * (1.f / D_MODEL);
    const float rstd = rsqrtf(var + 1e-5f);

    const float4 w0 = *(const float4*)(w + tid*8), w1 = *(const float4*)(w + tid*8 + 4);
    const float4 b0 = *(const float4*)(b + tid*8), b1 = *(const float4*)(b + tid*8 + 4);
    const float wv8[8] = {w0.x,w0.y,w0.z,w0.w,w1.x,w1.y,w1.z,w1.w};
    const float bv8[8] = {b0.x,b0.y,b0.z,b0.w,b1.x,b1.y,b1.z,b1.w};
    us8 o8;
#pragma unroll
    for (int i = 0; i < 8; i++)
        o8[i] = f2bf((e[i] - mean) * rstd * wv8[i] + bv8[i]);
    *(us8*)(out + (long)row * D_MODEL + tid*8) = o8;
}

// ---------------------------------------------------------------- RoPE in-place, Q|K fused
// heads 0..31 = Q (scale 1), heads 32..39 = K (scale 1/8). 4 pairs/thread, 16B ld/st.
#define ROPE_H 40
__global__ __launch_bounds__(256) void rope_k(ushort* __restrict__ x)
{
    const int idx = blockIdx.x * 256 + threadIdx.x;
    const int g  = idx & 7;              // group of 4 pairs
    const int h_ = (idx >> 3) % ROPE_H;
    const int s  = (idx >> 3) / ROPE_H;
    const float scale = (h_ < NH) ? 1.f : 0.125f;
    ushort* p = x + (long)s * QKV_DIM + h_ * HD + g * 8;
    us8 v = *(const us8*)p;
#pragma unroll
    for (int j = 0; j < 4; j++) {
        const int fi = g * 4 + j;
        // powf(10000, -2*fi/64) == exp2f(-fi * log2(10000)/32)
        const float freq = exp2f((float)fi * -0.41524101186f);
        float sn, cs;
        sincosf((float)s * freq, &sn, &cs);
        const float xr = bf2f(v[2*j]), xi = bf2f(v[2*j+1]);
        v[2*j]   = f2bf((xr * cs - xi * sn) * scale);
        v[2*j+1] = f2bf((xr * sn + xi * cs) * scale);
    }
    *(us8*)p = v;
}

// ---------------------------------------------------------------- transpose + cvt (all weights, 1 launch)
// 64x64 tile, 256 threads, float4 loads, ushort8 stores. All dims /64.
struct TcvtDesc {
    const float* src[7];
    ushort* dst[7];
    int ldin[7];
    int ldout[7];
    int gx[7];
    int blk0[8];
};
__global__ __launch_bounds__(256) void transcvt_all_k(TcvtDesc d)
{
    const int bid = blockIdx.x;
    int seg = 0;
#pragma unroll
    for (int i = 1; i < 7; i++) if (bid >= d.blk0[i]) seg = i;
    const int lb = bid - d.blk0[seg];
    const int gx = d.gx[seg];
    const int bx = lb % gx, by = lb / gx;
    const float* in = d.src[seg];
    ushort* out = d.dst[seg];
    const int ldin = d.ldin[seg], ldout = d.ldout[seg];

    __shared__ ushort tile[64][68];      // row stride 136 B: 8B-aligned, odd bank step
    const long c0 = (long)bx * 64, r0 = (long)by * 64;
    const int tid = threadIdx.x;

    const int lr = tid >> 4, lc = (tid & 15) * 4;
#pragma unroll
    for (int i = 0; i < 4; i++) {
        const float4 f = *(const float4*)(in + (r0 + lr + i*16) * (long)ldin + c0 + lc);
        us4 u; u[0] = f2bf(f.x); u[1] = f2bf(f.y); u[2] = f2bf(f.z); u[3] = f2bf(f.w);
        *(us4*)&tile[lr + i*16][lc] = u;
    }
    __syncthreads();

    const int oc = tid >> 3, orc = (tid & 7) * 8;
#pragma unroll
    for (int i = 0; i < 2; i++) {
        const int c = oc + i*32;
        us8 o;
#pragma unroll
        for (int j = 0; j < 8; j++) o[j] = tile[orc + j][c];
        *(us8*)(out + (c0 + c) * (long)ldout + r0 + orc) = o;
    }
}

// ---------------------------------------------------------------- transpose bf16 (V)
__global__ void transpose_k(const ushort* __restrict__ in, ushort* __restrict__ out,
                            int R, int C, int ldin, int ldout, long inB, long outB)
{
    __shared__ ushort tile[32][33];
    const long b = blockIdx.z;
    in += b * inB; out += b * outB;
    const int c0 = blockIdx.x * 32, r0 = blockIdx.y * 32;
    for (int i = threadIdx.y; i < 32; i += 8) {
        const int r = r0 + i, c = c0 + threadIdx.x;
        if (r < R && c < C) tile[i][threadIdx.x] = in[(long)r * ldin + c];
    }
    __syncthreads();
    for (int i = threadIdx.y; i < 32; i += 8) {
        const int c = c0 + i, r = r0 + threadIdx.x;
        if (r < R && c < C) out[(long)c * ldout + r] = tile[threadIdx.x][i];
    }
}

// ---------------------------------------------------------------- launch
extern "C" void kernel_launch(void* const* d_in, const int* in_sizes, int n_in,
                              void* d_out, int out_size, void* d_ws, size_t ws_size,
                              hipStream_t stream)
{
    const float* x   = (const float*)d_in[0];
    const float* wq  = (const float*)d_in[2];
    const float* wk  = (const float*)d_in[3];
    const float* wv  = (const float*)d_in[4];
    const float* wo  = (const float*)d_in[5];
    const float* w1  = (const float*)d_in[6];
    const float* w2  = (const float*)d_in[7];
    const float* w3  = (const float*)d_in[8];
    const float* ln1w = (const float*)d_in[9];
    const float* ln1b = (const float*)d_in[10];
    const float* ln2w = (const float*)d_in[11];
    const float* ln2b = (const float*)d_in[12];
    float* out = (float*)d_out;

    char* p = (char*)d_ws;
    auto alloc = [&](size_t bytes) {
        char* r = p; p += (bytes + 255) & ~(size_t)255; return r;
    };
    ushort* h      = (ushort*)alloc((size_t)S_LEN * D_MODEL * 2);
    ushort* qkv    = (ushort*)alloc((size_t)S_LEN * QKV_DIM * 2);
    ushort* vT     = (ushort*)alloc((size_t)NKV * HD * S_LEN * 2);
    ushort* attn   = (ushort*)alloc((size_t)S_LEN * D_MODEL * 2);
    float*  x1     = (float*) alloc((size_t)S_LEN * D_MODEL * 4);
    ushort* g1     = (ushort*)alloc((size_t)S_LEN * HID_DIM * 2);
    ushort* wqkvT  = (ushort*)alloc((size_t)QKV_DIM * D_MODEL * 2);
    ushort* woT    = (ushort*)alloc((size_t)D_MODEL * D_MODEL * 2);
    ushort* w1T    = (ushort*)alloc((size_t)D_MODEL * HID_DIM * 2);
    ushort* w2T    = (ushort*)alloc((size_t)D_MODEL * HID_DIM * 2);
    ushort* w3T    = (ushort*)alloc((size_t)D_MODEL * HID_DIM * 2);

    ushort* h2 = h;   // h dead after QKV

    const dim3 blk(256);
    const dim3 tb(32, 8);

    // all weight transposes + fp32->bf16 in ONE launch
    TcvtDesc d;
    d.src[0]=wq; d.src[1]=wk; d.src[2]=wv; d.src[3]=wo; d.src[4]=w1; d.src[5]=w3; d.src[6]=w2;
    d.dst[0]=wqkvT;
    d.dst[1]=wqkvT + (size_t)D_MODEL*D_MODEL;
    d.dst[2]=wqkvT + (size_t)(D_MODEL+KV_DIM)*D_MODEL;
    d.dst[3]=woT; d.dst[4]=w1T; d.dst[5]=w3T; d.dst[6]=w2T;
    d.ldin[0]=D_MODEL; d.ldin[1]=KV_DIM;  d.ldin[2]=KV_DIM;  d.ldin[3]=D_MODEL;
    d.ldin[4]=HID_DIM; d.ldin[5]=HID_DIM; d.ldin[6]=D_MODEL;
    d.ldout[0]=D_MODEL; d.ldout[1]=D_MODEL; d.ldout[2]=D_MODEL; d.ldout[3]=D_MODEL;
    d.ldout[4]=D_MODEL; d.ldout[5]=D_MODEL; d.ldout[6]=HID_DIM;
    d.gx[0]=32; d.gx[1]=8; d.gx[2]=8; d.gx[3]=32; d.gx[4]=88; d.gx[5]=88; d.gx[6]=32;
    // gy:        32        32         32          32          32          32          88
    d.blk0[0]=0; d.blk0[1]=1024; d.blk0[2]=1280; d.blk0[3]=1536; d.blk0[4]=2560;
    d.blk0[5]=5376; d.blk0[6]=8192; d.blk0[7]=11008;
    transcvt_all_k<<<11008, blk, 0, stream>>>(d);

    // LN1
    layernorm_k<<<S_LEN, blk, 0, stream>>>(x, ln1w, ln1b, h);

    // fused QKV projection (BN=64)
    gemm_bt<64><<<dim3(QKV_DIM/64, 16), blk, 0, stream>>>(
        h, wqkvT, qkv, D_MODEL, D_MODEL, D_MODEL, QKV_DIM, 1.f);

    // RoPE Q|K fused (scale 1/8 folded into K)
    rope_k<<<(S_LEN*ROPE_H*8)/256, blk, 0, stream>>>(qkv);

    // V transpose per KV head: vT[h][d][s]
    transpose_k<<<dim3(2, 64, NKV), tb, 0, stream>>>(
        qkv + D_MODEL + KV_DIM, vT, S_LEN, HD, QKV_DIM, S_LEN, (long)HD, (long)HD * S_LEN);

    // flash attention
    flash_attn_k<<<dim3(NH, S_LEN/128), blk, 0, stream>>>(qkv, vT, attn);

    // wo projection + residual -> fp32 x1
    gemm_bt_res<<<dim3(32, 16), blk, 0, stream>>>(
        attn, woT, x, x1, D_MODEL, D_MODEL, D_MODEL, D_MODEL);

    // LN2 + fused FFN up + down+residual
    layernorm_k<<<S_LEN, blk, 0, stream>>>(x1, ln2w, ln2b, h2);
    gemm_ffn13<<<dim3(HID_DIM/64, 16), blk, 0, stream>>>(h2, w1T, w3T, g1);
    gemm_bt_res<<<dim3(32, 16), blk, 0, stream>>>(
        g1, w2T, x1, out, HID_DIM, HID_DIM, HID_DIM, D_MODEL);
}